// Round 4
// baseline (129.655 us; speedup 1.0000x reference)
//
#include <hip/hip_runtime.h>

// ARMA posterior: math reduces exactly to (verified R3):
//   param[s,t,c] = z + A[t,c]*param[s,t-1,c],  z = mean[t,c] + sv[t,c]*noise
//   lp[s,t,c]    = nls[t,c] - 0.5*noise^2
// with c = 32 chains (D*P), A[0]=0. Inputs f32, outputs f32 (R2 evidence).
#define T_DIM 1024
#define D_DIM 4
#define P_DIM 8
#define S_DIM 256
#define DP 32
#define TDP (T_DIM * DP)      // 32768
#define LOG2PI_F 1.8378770664093453f

// ---------------------------------------------------------------------------
// Kernel A: SoA table planes: tbl[0]=mean, tbl[TDP]=sv, tbl[2T]=nls, tbl[3T]=A
// ---------------------------------------------------------------------------
__global__ __launch_bounds__(256) void build_tbl(
    const float* __restrict__ m,
    const float* __restrict__ s_raw,
    const float* __restrict__ a_raw,
    const int* __restrict__ dim_idx,
    float* __restrict__ tbl)
{
    int idx = blockIdx.x * 256 + threadIdx.x;   // covers TDP
    int t = idx >> 5, dp = idx & 31, d = dp >> 3, p = dp & 7;
    int di = dim_idx[d];

    float mm = m[(t * D_DIM + di) * P_DIM + p];
    float sr = s_raw[(t * D_DIM + di) * P_DIM + p];
    float sv = (sr > 20.0f) ? sr : log1pf(expf(sr));
    float A = 0.0f;
    if (t > 0) A = 1.0f / (1.0f + expf(-a_raw[(t - 1) * D_DIM + di]));

    tbl[idx]           = (1.0f - A) * mm;           // mean
    tbl[TDP + idx]     = sv;                        // sv
    tbl[2 * TDP + idx] = -logf(sv) - 0.5f * LOG2PI_F; // nls
    tbl[3 * TDP + idx] = A;                         // A
}

// ---------------------------------------------------------------------------
// Kernel B: whole-T scan, one block per sample, 1024 threads = 16 waves.
// tid = cj*8 + qc: cj in [0,128) time-chunks of 8 steps; qc in [0,8) quads
// of 4 chains (float4). Per 8-lane qc-group: 128 B contiguous row -> perfect
// coalescing. Carry combine: in-wave shfl scan (8 chunks/wave) + serial-16
// over wave totals + exclusive fixup. Exactly 2 __syncthreads total.
// ---------------------------------------------------------------------------
__global__ __launch_bounds__(1024) void scan_kernel(
    const float* __restrict__ noise,
    const float* __restrict__ tbl,
    float* __restrict__ param_out,
    float* __restrict__ lp_out)
{
    const int tid  = threadIdx.x;
    const int qc   = tid & 7;          // chain quad
    const int cj   = tid >> 3;         // time chunk 0..127
    const int cjw  = cj & 7;           // chunk within wave
    const int wg   = tid >> 6;         // wave 0..15

    __shared__ float wtp[16][32];      // wave-total p
    __shared__ float wtm[16][32];      // wave-total m
    __shared__ float wci[16][32];      // exclusive carry per wave

    const size_t sbase = (size_t)blockIdx.x * TDP;
    const int    off0  = cj * 8 * DP + qc * 4;

    // ---- local 8-step scan over 4 chains; lp stored inline
    float4 pl[8], Mk[8];
    float4 rp = make_float4(0.f, 0.f, 0.f, 0.f);
    float4 rm = make_float4(1.f, 1.f, 1.f, 1.f);
#pragma unroll
    for (int k = 0; k < 8; ++k) {
        const int o = off0 + k * DP;
        const float4 n  = *(const float4*)(noise + sbase + o);
        const float4 me = *(const float4*)(tbl + o);
        const float4 sv = *(const float4*)(tbl + TDP + o);
        const float4 nl = *(const float4*)(tbl + 2 * TDP + o);
        const float4 Aa = *(const float4*)(tbl + 3 * TDP + o);

        float4 lp;
        lp.x = nl.x - 0.5f * n.x * n.x;
        lp.y = nl.y - 0.5f * n.y * n.y;
        lp.z = nl.z - 0.5f * n.z * n.z;
        lp.w = nl.w - 0.5f * n.w * n.w;
        *(float4*)(lp_out + sbase + o) = lp;

        float4 z;
        z.x = me.x + sv.x * n.x;
        z.y = me.y + sv.y * n.y;
        z.z = me.z + sv.z * n.z;
        z.w = me.w + sv.w * n.w;

        rp.x = z.x + Aa.x * rp.x;  rm.x *= Aa.x;
        rp.y = z.y + Aa.y * rp.y;  rm.y *= Aa.y;
        rp.z = z.z + Aa.z * rp.z;  rm.z *= Aa.z;
        rp.w = z.w + Aa.w * rp.w;  rm.w *= Aa.w;
        pl[k] = rp;
        Mk[k] = rm;
    }

    // ---- Phase A: inclusive shfl-scan over the 8 chunks within each wave
    //      combine(older(p1,m1), newer(p2,m2)) = (p2 + m2*p1, m1*m2)
#pragma unroll
    for (int off = 1; off < 8; off <<= 1) {
        const int d = off * 8;   // lanes per chunk step
        float4 pp, pm;
        pp.x = __shfl_up(rp.x, d, 64);  pm.x = __shfl_up(rm.x, d, 64);
        pp.y = __shfl_up(rp.y, d, 64);  pm.y = __shfl_up(rm.y, d, 64);
        pp.z = __shfl_up(rp.z, d, 64);  pm.z = __shfl_up(rm.z, d, 64);
        pp.w = __shfl_up(rp.w, d, 64);  pm.w = __shfl_up(rm.w, d, 64);
        if (cjw >= off) {
            rp.x += rm.x * pp.x;  rm.x *= pm.x;
            rp.y += rm.y * pp.y;  rm.y *= pm.y;
            rp.z += rm.z * pp.z;  rm.z *= pm.z;
            rp.w += rm.w * pp.w;  rm.w *= pm.w;
        }
    }

    // ---- Phase B: wave totals -> serial scan over 16 waves (32 lanes)
    if (cjw == 7) {
        *(float4*)&wtp[wg][qc * 4] = rp;
        *(float4*)&wtm[wg][qc * 4] = rm;
    }
    __syncthreads();
    if (tid < 32) {
        float c = 0.0f;
#pragma unroll
        for (int g = 0; g < 16; ++g) {
            wci[g][tid] = c;
            c = wtp[g][tid] + wtm[g][tid] * c;
        }
    }
    __syncthreads();

    // ---- Phase C: thread carry-in = excl-in-wave applied on wave carry
    float4 ep, em;
    ep.x = __shfl_up(rp.x, 8, 64);  em.x = __shfl_up(rm.x, 8, 64);
    ep.y = __shfl_up(rp.y, 8, 64);  em.y = __shfl_up(rm.y, 8, 64);
    ep.z = __shfl_up(rp.z, 8, 64);  em.z = __shfl_up(rm.z, 8, 64);
    ep.w = __shfl_up(rp.w, 8, 64);  em.w = __shfl_up(rm.w, 8, 64);
    if (cjw == 0) {
        ep = make_float4(0.f, 0.f, 0.f, 0.f);
        em = make_float4(1.f, 1.f, 1.f, 1.f);
    }
    const float4 ci = *(const float4*)&wci[wg][qc * 4];
    float4 carry;
    carry.x = ep.x + em.x * ci.x;
    carry.y = ep.y + em.y * ci.y;
    carry.z = ep.z + em.z * ci.z;
    carry.w = ep.w + em.w * ci.w;

#pragma unroll
    for (int k = 0; k < 8; ++k) {
        const int o = off0 + k * DP;
        float4 pv;
        pv.x = pl[k].x + Mk[k].x * carry.x;
        pv.y = pl[k].y + Mk[k].y * carry.y;
        pv.z = pl[k].z + Mk[k].z * carry.z;
        pv.w = pl[k].w + Mk[k].w * carry.w;
        *(float4*)(param_out + sbase + o) = pv;
    }
}

// ---------------------------------------------------------------------------
extern "C" void kernel_launch(void* const* d_in, const int* in_sizes, int n_in,
                              void* d_out, int out_size, void* d_ws, size_t ws_size,
                              hipStream_t stream)
{
    // 0:y 1:age 2:m(T,D,P) 3:s_raw(T,D,P) 4:a_raw(T-1,D,1) 5:noise(S,T,D,P)
    // 6:cond_sample 7:dim_idx(D) 8:compute_log_prob
    const float* m      = (const float*)d_in[2];
    const float* s_raw  = (const float*)d_in[3];
    const float* a_raw  = (const float*)d_in[4];
    const float* noise  = (const float*)d_in[5];
    const int*   dimidx = (const int*)d_in[7];

    float* tbl = (float*)d_ws;                    // 4 planes * 128 KB = 512 KB

    float* param_out = (float*)d_out;
    float* lp_out    = param_out + (size_t)S_DIM * TDP;

    build_tbl<<<TDP / 256, 256, 0, stream>>>(m, s_raw, a_raw, dimidx, tbl);
    scan_kernel<<<S_DIM, 1024, 0, stream>>>(noise, tbl, param_out, lp_out);
}

// Round 6
// 119.189 us; speedup vs baseline: 1.0878x; 1.0878x over previous
//
#include <hip/hip_runtime.h>

// ARMA posterior (math verified R3): per chain c in DP=32, sample s:
//   A[t,c]   = sigmoid(a_raw[t-1, dim_idx[d]])   (A[0]=0; same for all p in d)
//   sv[t,c]  = softplus(s_raw[t, dim_idx[d], p])
//   z        = (1-A)*m[t,di,p] + sv*noise
//   param[t] = z + A*param[t-1]
//   lp[t]    = -log(sv) - 0.5*log2pi - 0.5*noise^2
// Inputs f32, outputs f32 (R2 evidence). Single fused kernel; nontemporal
// builtins need clang ext_vector_type, not HIP_vector_type (R5 compile fix).
#define T_DIM 1024
#define D_DIM 4
#define P_DIM 8
#define S_DIM 256
#define DP 32
#define TDP (T_DIM * DP)      // 32768 per sample
#define LOG2PI_F 1.8378770664093453f

typedef float vf4 __attribute__((ext_vector_type(4)));

__global__ __launch_bounds__(1024) void fused_scan(
    const float* __restrict__ noise,
    const float* __restrict__ m,
    const float* __restrict__ s_raw,
    const float* __restrict__ a_raw,
    const int* __restrict__ dim_idx,
    float* __restrict__ param_out,
    float* __restrict__ lp_out)
{
    const int tid = threadIdx.x;
    const int qc  = tid & 7;           // chain quad 0..7
    const int cj  = tid >> 3;          // time chunk 0..127 (8 steps each)
    const int cjw = cj & 7;            // chunk within wave
    const int wg  = tid >> 6;          // wave 0..15

    const int d  = qc >> 1;            // output dim 0..3
    const int p0 = (qc & 1) * 4;       // first of 4 consecutive p
    const int di = dim_idx[d];

    __shared__ float wtp[16][32];      // wave-total p
    __shared__ float wtm[16][32];      // wave-total m
    __shared__ float wci[16][32];      // exclusive carry-in per wave

    const size_t sbase = (size_t)blockIdx.x * TDP;
    const int    off0  = cj * 8 * DP + qc * 4;

    // ---- Phase 0: local 8-step scan over 4 chains; table computed inline
    vf4 pl[8], Mk[8];
    vf4 rp = (vf4){0.f, 0.f, 0.f, 0.f};
    vf4 rm = (vf4){1.f, 1.f, 1.f, 1.f};
#pragma unroll
    for (int k = 0; k < 8; ++k) {
        const int t = cj * 8 + k;
        const int o = off0 + k * DP;
        const vf4 n  = __builtin_nontemporal_load((const vf4*)(noise + sbase + o));
        const vf4 mv = *(const vf4*)(m     + (t * D_DIM + di) * P_DIM + p0);
        const vf4 sr = *(const vf4*)(s_raw + (t * D_DIM + di) * P_DIM + p0);

        // A: per-(t,d) scalar, shared by the 4 chains of this thread
        float A = 0.0f;
        if (t > 0) A = 1.0f / (1.0f + __expf(-a_raw[(t - 1) * D_DIM + di]));
        const float oma = 1.0f - A;

        // softplus + nls per chain
        vf4 sv, nl;
        sv.x = __logf(1.0f + __expf(sr.x));  nl.x = -__logf(sv.x) - 0.5f * LOG2PI_F;
        sv.y = __logf(1.0f + __expf(sr.y));  nl.y = -__logf(sv.y) - 0.5f * LOG2PI_F;
        sv.z = __logf(1.0f + __expf(sr.z));  nl.z = -__logf(sv.z) - 0.5f * LOG2PI_F;
        sv.w = __logf(1.0f + __expf(sr.w));  nl.w = -__logf(sv.w) - 0.5f * LOG2PI_F;

        vf4 lp;
        lp.x = nl.x - 0.5f * n.x * n.x;
        lp.y = nl.y - 0.5f * n.y * n.y;
        lp.z = nl.z - 0.5f * n.z * n.z;
        lp.w = nl.w - 0.5f * n.w * n.w;
        __builtin_nontemporal_store(lp, (vf4*)(lp_out + sbase + o));

        vf4 z;
        z.x = oma * mv.x + sv.x * n.x;
        z.y = oma * mv.y + sv.y * n.y;
        z.z = oma * mv.z + sv.z * n.z;
        z.w = oma * mv.w + sv.w * n.w;

        rp.x = z.x + A * rp.x;  rm.x *= A;
        rp.y = z.y + A * rp.y;  rm.y *= A;
        rp.z = z.z + A * rp.z;  rm.z *= A;
        rp.w = z.w + A * rp.w;  rm.w *= A;
        pl[k] = rp;
        Mk[k] = rm;
    }

    // ---- Phase A: inclusive shfl-scan over 8 chunks within each wave
    //      combine(older(p1,m1), newer(p2,m2)) = (p2 + m2*p1, m1*m2)
#pragma unroll
    for (int off = 1; off < 8; off <<= 1) {
        const int dd = off * 8;        // lanes per chunk step
        vf4 pp, pm;
        pp.x = __shfl_up(rp.x, dd, 64);  pm.x = __shfl_up(rm.x, dd, 64);
        pp.y = __shfl_up(rp.y, dd, 64);  pm.y = __shfl_up(rm.y, dd, 64);
        pp.z = __shfl_up(rp.z, dd, 64);  pm.z = __shfl_up(rm.z, dd, 64);
        pp.w = __shfl_up(rp.w, dd, 64);  pm.w = __shfl_up(rm.w, dd, 64);
        if (cjw >= off) {
            rp.x += rm.x * pp.x;  rm.x *= pm.x;
            rp.y += rm.y * pp.y;  rm.y *= pm.y;
            rp.z += rm.z * pp.z;  rm.z *= pm.z;
            rp.w += rm.w * pp.w;  rm.w *= pm.w;
        }
    }

    // ---- Phase B: wave totals -> serial scan over 16 waves (32 lanes)
    if (cjw == 7) {
        *(vf4*)&wtp[wg][qc * 4] = rp;
        *(vf4*)&wtm[wg][qc * 4] = rm;
    }
    __syncthreads();
    if (tid < 32) {
        float c = 0.0f;
#pragma unroll
        for (int g = 0; g < 16; ++g) {
            wci[g][tid] = c;
            c = wtp[g][tid] + wtm[g][tid] * c;
        }
    }
    __syncthreads();

    // ---- Phase C: per-thread carry-in = excl-in-wave composed on wave carry
    vf4 ep, em;
    ep.x = __shfl_up(rp.x, 8, 64);  em.x = __shfl_up(rm.x, 8, 64);
    ep.y = __shfl_up(rp.y, 8, 64);  em.y = __shfl_up(rm.y, 8, 64);
    ep.z = __shfl_up(rp.z, 8, 64);  em.z = __shfl_up(rm.z, 8, 64);
    ep.w = __shfl_up(rp.w, 8, 64);  em.w = __shfl_up(rm.w, 8, 64);
    if (cjw == 0) {
        ep = (vf4){0.f, 0.f, 0.f, 0.f};
        em = (vf4){1.f, 1.f, 1.f, 1.f};
    }
    const vf4 ci = *(const vf4*)&wci[wg][qc * 4];
    vf4 carry;
    carry.x = ep.x + em.x * ci.x;
    carry.y = ep.y + em.y * ci.y;
    carry.z = ep.z + em.z * ci.z;
    carry.w = ep.w + em.w * ci.w;

#pragma unroll
    for (int k = 0; k < 8; ++k) {
        const int o = off0 + k * DP;
        vf4 pv;
        pv.x = pl[k].x + Mk[k].x * carry.x;
        pv.y = pl[k].y + Mk[k].y * carry.y;
        pv.z = pl[k].z + Mk[k].z * carry.z;
        pv.w = pl[k].w + Mk[k].w * carry.w;
        __builtin_nontemporal_store(pv, (vf4*)(param_out + sbase + o));
    }
}

// ---------------------------------------------------------------------------
extern "C" void kernel_launch(void* const* d_in, const int* in_sizes, int n_in,
                              void* d_out, int out_size, void* d_ws, size_t ws_size,
                              hipStream_t stream)
{
    // 0:y 1:age 2:m(T,D,P) 3:s_raw(T,D,P) 4:a_raw(T-1,D,1) 5:noise(S,T,D,P)
    // 6:cond_sample 7:dim_idx(D) 8:compute_log_prob
    const float* m      = (const float*)d_in[2];
    const float* s_raw  = (const float*)d_in[3];
    const float* a_raw  = (const float*)d_in[4];
    const float* noise  = (const float*)d_in[5];
    const int*   dimidx = (const int*)d_in[7];

    float* param_out = (float*)d_out;
    float* lp_out    = param_out + (size_t)S_DIM * TDP;

    fused_scan<<<S_DIM, 1024, 0, stream>>>(noise, m, s_raw, a_raw, dimidx,
                                           param_out, lp_out);
}